// Round 3
// baseline (175.088 us; speedup 1.0000x reference)
//
#include <hip/hip_runtime.h>
#include <math.h>

// Problem constants
#define VDIM   128
#define KCODES 512
#define NROWS  (32 * 4096)      // 131072
#define TILE_ROWS 512           // rows per block (16 waves x 32 rows)
#define NBLK (NROWS / TILE_ROWS) // 256 blocks = exactly 1 per CU
#define TN 0.67882250993908565f // 0.06 * sqrt(128)

typedef __attribute__((ext_vector_type(8))) short bf16x8;  // MFMA A/B frag (4 VGPR)
typedef __attribute__((ext_vector_type(4))) float f32x4;   // MFMA C/D frag / 16B ld-st

__device__ __forceinline__ unsigned short f2bf(float f) {
    unsigned u = __float_as_uint(f);
    unsigned r = u + 0x7FFFu + ((u >> 16) & 1u);   // round-to-nearest-even
    return (unsigned short)(r >> 16);
}

__device__ __forceinline__ bf16x8 pack8(f32x4 a, f32x4 b) {
    bf16x8 v;
    v[0] = (short)f2bf(a[0]); v[1] = (short)f2bf(a[1]);
    v[2] = (short)f2bf(a[2]); v[3] = (short)f2bf(a[3]);
    v[4] = (short)f2bf(b[0]); v[5] = (short)f2bf(b[1]);
    v[6] = (short)f2bf(b[2]); v[7] = (short)f2bf(b[3]);
    return v;
}

// Normalize codes. embn: fp32 row-major (epilogue gather).
// ebf: bf16 in MFMA *fragment-linear* layout so staging is a pure linear
// memcpy and ds_read_b128 of fragments is stride-1 (conflict-free):
//   granule G = (k>>4)*256 + (d>>3)*16 + (k&15) holds dims [d&~7, +8) of code k
__global__ void prep_emb(const float* __restrict__ emb0,
                         float* __restrict__ embn,
                         unsigned short* __restrict__ ebf) {
    int k = blockIdx.x;       // KCODES blocks
    int l = threadIdx.x;      // 64 threads = 1 wave
    const float* row = emb0 + (size_t)k * VDIM;
    float a = row[l];
    float b = row[l + 64];
    float ss = a * a + b * b;
    #pragma unroll
    for (int off = 32; off; off >>= 1) ss += __shfl_xor(ss, off);
    float nrm = sqrtf(ss);
    float ea = (TN * a) / nrm;
    float eb = (TN * b) / nrm;
    embn[(size_t)k * VDIM + l]      = ea;
    embn[(size_t)k * VDIM + l + 64] = eb;
    // fragment-linear bf16 table
    size_t base = ((size_t)(k >> 4) << 11) + ((size_t)(k & 15) << 3);
    int d1 = l;         // dim handled: l
    int d2 = l + 64;    // dim handled: l+64
    ebf[base + ((size_t)(d1 >> 3) << 7) + (d1 & 7)] = f2bf(ea);
    ebf[base + ((size_t)(d2 >> 3) << 7) + (d2 & 7)] = f2bf(eb);
}

// Main: 16 waves x 32 rows, 1 block per CU. The FULL 128 KB bf16 code table
// is staged into LDS ONCE (vs 512 MB of repeated L3 reads in the direct-L2
// variant, or 128 MB in the per-block-restaged variant). Main loop has zero
// barriers: B frags come from conflict-free stride-1 ds_read_b128.
// x0 loads are nontemporal (single-use stream; don't evict embn from L2).
// argmin(dist) == argmax(dot(x0,e)) since ||x|| = ||e|| = tn exactly.
__global__ __launch_bounds__(1024, 4) void vq_main(
        const float* __restrict__ x0,
        const unsigned short* __restrict__ ebf,
        const float* __restrict__ embn,
        unsigned* __restrict__ hist,
        float* __restrict__ out0,
        float* __restrict__ out1,
        float* __restrict__ out2) {
    __shared__ uint4 sB[8192];              // 128 KB: full fragment-linear table
    __shared__ int   sbesti[TILE_ROWS];
    __shared__ float sdot[TILE_ROWS];
    __shared__ float sn0[TILE_ROWS];

    int t = threadIdx.x;
    int w = t >> 6;           // wave 0..15
    int l = t & 63;
    int n15 = l & 15;         // MFMA m (A rows), n (B cols), col (C)
    int q = l >> 4;           // quad: input k = q*8 + j; C row = q*4 + r

    // ---- Stage full B table: 8 x (1024 threads x 16B) = 128 KB, linear copy
    const uint4* ebg = (const uint4*)ebf;
    #pragma unroll
    for (int r = 0; r < 8; ++r)
        sB[(r << 10) + t] = ebg[(r << 10) + t];

    // ---- Load A (overlaps the staging loads): 2 strips x 16 rows, nt loads
    int rowbase = blockIdx.x * TILE_ROWS + (w << 5);
    bf16x8 afr[2][4];
    float nsq[2];
    #pragma unroll
    for (int s = 0; s < 2; ++s) {
        const float* xrow = x0 + (size_t)(rowbase + (s << 4) + n15) * VDIM + (q << 3);
        float p0 = 0.f, p1 = 0.f;
        #pragma unroll
        for (int kc = 0; kc < 4; ++kc) {
            const f32x4* xp = (const f32x4*)(xrow + (kc << 5));
            f32x4 a = __builtin_nontemporal_load(xp);
            f32x4 b = __builtin_nontemporal_load(xp + 1);
            p0 = fmaf(a[0], a[0], p0); p1 = fmaf(a[1], a[1], p1);
            p0 = fmaf(a[2], a[2], p0); p1 = fmaf(a[3], a[3], p1);
            p0 = fmaf(b[0], b[0], p0); p1 = fmaf(b[1], b[1], p1);
            p0 = fmaf(b[2], b[2], p0); p1 = fmaf(b[3], b[3], p1);
            afr[s][kc] = pack8(a, b);
        }
        nsq[s] = p0 + p1;
        nsq[s] += __shfl_xor(nsq[s], 16, 64);   // reduce ||x0||^2 across quads
        nsq[s] += __shfl_xor(nsq[s], 32, 64);
    }

    float best[2][4];
    int   bidx[2][4];
    #pragma unroll
    for (int s = 0; s < 2; ++s)
        #pragma unroll
        for (int r = 0; r < 4; ++r) { best[s][r] = -3.4e38f; bidx[s][r] = 0; }

    const f32x4 zero4 = {0.f, 0.f, 0.f, 0.f};

    __syncthreads();    // staged table visible to all 16 waves

    // ---- 32 chunks of 16 codes, B frags from LDS (stride-1, conflict-free)
    #pragma unroll 2
    for (int cn = 0; cn < 32; ++cn) {
        const bf16x8* bls = ((const bf16x8*)sB) + (cn << 8) + l;
        bf16x8 b0 = bls[0], b1 = bls[64], b2 = bls[128], b3 = bls[192];
        int nbase = (cn << 4) + n15;
        #pragma unroll
        for (int s = 0; s < 2; ++s) {
            f32x4 acc = __builtin_amdgcn_mfma_f32_16x16x32_bf16(afr[s][0], b0, zero4, 0, 0, 0);
            acc = __builtin_amdgcn_mfma_f32_16x16x32_bf16(afr[s][1], b1, acc, 0, 0, 0);
            acc = __builtin_amdgcn_mfma_f32_16x16x32_bf16(afr[s][2], b2, acc, 0, 0, 0);
            acc = __builtin_amdgcn_mfma_f32_16x16x32_bf16(afr[s][3], b3, acc, 0, 0, 0);
            #pragma unroll
            for (int r = 0; r < 4; ++r) {
                float d = acc[r];
                if (d > best[s][r]) { best[s][r] = d; bidx[s][r] = nbase; }
            }
        }
    }

    // ---- Reduce argmax across the 16 lanes (C cols) holding the same row
    #pragma unroll
    for (int m = 1; m <= 8; m <<= 1) {
        #pragma unroll
        for (int s = 0; s < 2; ++s)
            #pragma unroll
            for (int r = 0; r < 4; ++r) {
                float ov = __shfl_xor(best[s][r], m, 64);
                int   oi = __shfl_xor(bidx[s][r], m, 64);
                if (ov > best[s][r] || (ov == best[s][r] && oi < bidx[s][r])) {
                    best[s][r] = ov; bidx[s][r] = oi;
                }
            }
    }

    // ---- Stage per-row results to LDS for the coalesced epilogue
    if (n15 == 0) {
        #pragma unroll
        for (int s = 0; s < 2; ++s)
            #pragma unroll
            for (int r = 0; r < 4; ++r) {
                int lr = (w << 5) + (s << 4) + (q << 2) + r;  // C row = q*4+r
                sbesti[lr] = bidx[s][r];
                sdot[lr]   = best[s][r];
            }
    }
    if (q == 0) {
        #pragma unroll
        for (int s = 0; s < 2; ++s) sn0[(w << 5) + (s << 4) + n15] = nsq[s];
    }
    __syncthreads();

    // ---- Epilogue A: coalesced out0 copy (32 lanes cover one row's 512 B)
    // Nontemporal stores: don't let the 64 MB output stream pollute caches.
    size_t blockrow = (size_t)blockIdx.x * TILE_ROWS;
    #pragma unroll
    for (int pass = 0; pass < 16; ++pass) {
        int lr = (pass << 5) + (t >> 5);   // 32 rows per pass
        int v4 = t & 31;                   // float4 slot within the row
        int bi = sbesti[lr];
        f32x4 e = *((const f32x4*)(embn + (size_t)bi * VDIM) + v4);
        __builtin_nontemporal_store(e, (f32x4*)(out0 + (blockrow + lr) * (size_t)VDIM) + v4);
    }

    // ---- Epilogue B: per-row scalars (threads 0..511)
    if (t < TILE_ROWS) {
        size_t row = blockrow + t;
        int bi = sbesti[t];
        float dotv = sdot[t];
        float nn = sn0[t];
        float sc = TN / sqrtf(nn);                      // x = sc * x0
        float o1 = 2.f * TN * TN - 2.f * sc * dotv;     // ||x||^2=||e||^2=tn^2
        __builtin_nontemporal_store(o1, &out1[row]);
        float sm = sc - 1.f;
        __builtin_nontemporal_store(o1 + sm * sm * nn, &out2[row]);
        atomicAdd(&hist[bi], 1u);
    }
}

__global__ void entropy_k(const unsigned* __restrict__ hist,
                          float* __restrict__ out) {
    __shared__ float red[8];
    int t = threadIdx.x;   // KCODES threads
    float h = (float)hist[t];
    float p = h / (float)NROWS;
    float term = (h > 0.f) ? p * logf(p) : 0.f;
    #pragma unroll
    for (int off = 32; off; off >>= 1) term += __shfl_xor(term, off);
    if ((t & 63) == 0) red[t >> 6] = term;
    __syncthreads();
    if (t == 0) {
        float ssum = 0.f;
        #pragma unroll
        for (int i = 0; i < 8; i++) ssum += red[i];
        out[0] = -ssum;
    }
}

extern "C" void kernel_launch(void* const* d_in, const int* in_sizes, int n_in,
                              void* d_out, int out_size, void* d_ws, size_t ws_size,
                              hipStream_t stream) {
    const float* x0   = (const float*)d_in[0];
    const float* emb0 = (const float*)d_in[1];

    float* embn = (float*)d_ws;                              // 512*128 f32 = 256 KB
    unsigned* hist = (unsigned*)(embn + (size_t)KCODES * VDIM); // 512 u32
    unsigned short* ebf = (unsigned short*)(hist + KCODES);  // 512*128 bf16 = 128 KB

    float* out  = (float*)d_out;
    float* out0 = out;
    float* out1 = out0 + (size_t)NROWS * VDIM;
    float* out2 = out1 + NROWS;
    float* oent = out2 + NROWS;

    hipMemsetAsync(hist, 0, KCODES * sizeof(unsigned), stream);
    prep_emb<<<KCODES, 64, 0, stream>>>(emb0, embn, ebf);
    vq_main<<<NBLK, 1024, 0, stream>>>(x0, ebf, embn, hist,
                                       out0, out1, out2);
    entropy_k<<<1, KCODES, 0, stream>>>(hist, oent);
}

// Round 4
// 166.459 us; speedup vs baseline: 1.0518x; 1.0518x over previous
//
#include <hip/hip_runtime.h>
#include <math.h>

// Problem constants
#define VDIM   128
#define KCODES 512
#define NROWS  (32 * 4096)       // 131072
#define TILE_ROWS 512            // rows per block (16 waves x 32 rows)
#define NBLK (NROWS / TILE_ROWS) // 256 blocks = exactly 1 per CU
#define TN 0.67882250993908565f  // 0.06 * sqrt(128)

typedef __attribute__((ext_vector_type(8))) short bf16x8;  // MFMA A/B frag (4 VGPR)
typedef __attribute__((ext_vector_type(4))) float f32x4;   // MFMA C/D frag / 16B ld-st

__device__ __forceinline__ unsigned short f2bf(float f) {
    unsigned u = __float_as_uint(f);
    unsigned r = u + 0x7FFFu + ((u >> 16) & 1u);   // round-to-nearest-even
    return (unsigned short)(r >> 16);
}

__device__ __forceinline__ bf16x8 pack8(f32x4 a, f32x4 b) {
    bf16x8 v;
    v[0] = (short)f2bf(a[0]); v[1] = (short)f2bf(a[1]);
    v[2] = (short)f2bf(a[2]); v[3] = (short)f2bf(a[3]);
    v[4] = (short)f2bf(b[0]); v[5] = (short)f2bf(b[1]);
    v[6] = (short)f2bf(b[2]); v[7] = (short)f2bf(b[3]);
    return v;
}

// ONE fused kernel: per-block code normalization + in-LDS fragment table build
// + MFMA argmax + epilogue. 16 waves x 32 rows, 1 block per CU.
// - x0 loads issued first (nt), latency hidden under the normalize phase.
// - bf16 table built straight into LDS (fragment-linear granules,
//   conflict-free ds_write_b128); no global ebf/embn round-trip, no prep kernel.
// - histogram via LDS atomics -> u16 partials per block (no global atomic
//   contention, no memset dispatch).
// argmin(dist) == argmax(dot(x0,e)) since ||x|| = ||e|| = tn exactly.
__global__ __launch_bounds__(1024, 4) void vq_fused(
        const float* __restrict__ x0,
        const float* __restrict__ emb0,
        unsigned short* __restrict__ hist_part,
        float* __restrict__ out0,
        float* __restrict__ out1,
        float* __restrict__ out2) {
    __shared__ uint4 sB[8192];              // 128 KB fragment-linear bf16 table
    __shared__ float sscale[KCODES];        // TN / ||emb0_k||
    __shared__ int   shist[KCODES];         // per-block histogram
    __shared__ int   sbesti[TILE_ROWS];
    __shared__ float sdot[TILE_ROWS];
    __shared__ float sn0[TILE_ROWS];

    int t = threadIdx.x;
    int w = t >> 6;           // wave 0..15
    int l = t & 63;
    int n15 = l & 15;         // MFMA m (A rows), n (B cols), col (C)
    int q = l >> 4;           // quad: input k = q*8 + j; C row = q*4 + r

    // ---- Issue x0 loads FIRST (nt: single-use stream, keep emb0 in L2).
    // Latency hides under the normalize + table-build phases below.
    int rowbase = blockIdx.x * TILE_ROWS + (w << 5);
    f32x4 ax[2][4][2];
    #pragma unroll
    for (int s = 0; s < 2; ++s) {
        const float* xrow = x0 + (size_t)(rowbase + (s << 4) + n15) * VDIM + (q << 3);
        #pragma unroll
        for (int kc = 0; kc < 4; ++kc) {
            const f32x4* xp = (const f32x4*)(xrow + (kc << 5));
            ax[s][kc][0] = __builtin_nontemporal_load(xp);
            ax[s][kc][1] = __builtin_nontemporal_load(xp + 1);
        }
    }

    if (t < KCODES) shist[t] = 0;

    // ---- Phase 1a: code norms. Wave w handles codes w*32 .. w*32+31.
    #pragma unroll 4
    for (int i = 0; i < 32; ++i) {
        int k = (w << 5) + i;
        const float* row = emb0 + (size_t)k * VDIM;
        float a = row[l];
        float b = row[l + 64];
        float ss = a * a + b * b;
        #pragma unroll
        for (int off = 32; off; off >>= 1) ss += __shfl_xor(ss, off);
        if (l == 0) sscale[k] = TN / sqrtf(ss);
    }
    __syncthreads();        // sscale + shist-zero visible

    // ---- Phase 1b: build fragment-linear table in LDS.
    // Granule g holds dims [d0, d0+8) of code k, where
    //   k = (g>>8)*16 + (g&15),  d0 = ((g>>4)&15)*8.
    // Thread t writes granules t, t+1024, ... : stride-1 ds_write_b128.
    #pragma unroll
    for (int i = 0; i < 8; ++i) {
        int g = (i << 10) + t;
        int k = ((g >> 8) << 4) | (g & 15);
        int d0 = ((g >> 4) & 15) << 3;
        float s = sscale[k];
        const f32x4* ep = (const f32x4*)(emb0 + (size_t)k * VDIM + d0);
        f32x4 a = ep[0], b = ep[1];
        f32x4 as, bs;
        as[0] = a[0] * s; as[1] = a[1] * s; as[2] = a[2] * s; as[3] = a[3] * s;
        bs[0] = b[0] * s; bs[1] = b[1] * s; bs[2] = b[2] * s; bs[3] = b[3] * s;
        ((bf16x8*)sB)[g] = pack8(as, bs);
    }

    // ---- Pack A from the (by now arrived) x0 registers; overlaps LDS writes.
    bf16x8 afr[2][4];
    float nsq[2];
    #pragma unroll
    for (int s = 0; s < 2; ++s) {
        float p0 = 0.f, p1 = 0.f;
        #pragma unroll
        for (int kc = 0; kc < 4; ++kc) {
            f32x4 a = ax[s][kc][0], b = ax[s][kc][1];
            p0 = fmaf(a[0], a[0], p0); p1 = fmaf(a[1], a[1], p1);
            p0 = fmaf(a[2], a[2], p0); p1 = fmaf(a[3], a[3], p1);
            p0 = fmaf(b[0], b[0], p0); p1 = fmaf(b[1], b[1], p1);
            p0 = fmaf(b[2], b[2], p0); p1 = fmaf(b[3], b[3], p1);
            afr[s][kc] = pack8(a, b);
        }
        nsq[s] = p0 + p1;
        nsq[s] += __shfl_xor(nsq[s], 16, 64);   // reduce ||x0||^2 across quads
        nsq[s] += __shfl_xor(nsq[s], 32, 64);
    }

    float best[2][4];
    int   bidx[2][4];
    #pragma unroll
    for (int s = 0; s < 2; ++s)
        #pragma unroll
        for (int r = 0; r < 4; ++r) { best[s][r] = -3.4e38f; bidx[s][r] = 0; }

    const f32x4 zero4 = {0.f, 0.f, 0.f, 0.f};

    __syncthreads();        // table fully built

    // ---- 32 chunks of 16 codes, B frags from LDS (stride-1, conflict-free)
    #pragma unroll 2
    for (int cn = 0; cn < 32; ++cn) {
        const bf16x8* bls = ((const bf16x8*)sB) + (cn << 8) + l;
        bf16x8 b0 = bls[0], b1 = bls[64], b2 = bls[128], b3 = bls[192];
        int nbase = (cn << 4) + n15;
        #pragma unroll
        for (int s = 0; s < 2; ++s) {
            f32x4 acc = __builtin_amdgcn_mfma_f32_16x16x32_bf16(afr[s][0], b0, zero4, 0, 0, 0);
            acc = __builtin_amdgcn_mfma_f32_16x16x32_bf16(afr[s][1], b1, acc, 0, 0, 0);
            acc = __builtin_amdgcn_mfma_f32_16x16x32_bf16(afr[s][2], b2, acc, 0, 0, 0);
            acc = __builtin_amdgcn_mfma_f32_16x16x32_bf16(afr[s][3], b3, acc, 0, 0, 0);
            #pragma unroll
            for (int r = 0; r < 4; ++r) {
                float d = acc[r];
                if (d > best[s][r]) { best[s][r] = d; bidx[s][r] = nbase; }
            }
        }
    }

    // ---- Reduce argmax across the 16 lanes (C cols) holding the same row
    #pragma unroll
    for (int m = 1; m <= 8; m <<= 1) {
        #pragma unroll
        for (int s = 0; s < 2; ++s)
            #pragma unroll
            for (int r = 0; r < 4; ++r) {
                float ov = __shfl_xor(best[s][r], m, 64);
                int   oi = __shfl_xor(bidx[s][r], m, 64);
                if (ov > best[s][r] || (ov == best[s][r] && oi < bidx[s][r])) {
                    best[s][r] = ov; bidx[s][r] = oi;
                }
            }
    }

    // ---- Stage per-row results to LDS for the coalesced epilogue
    if (n15 == 0) {
        #pragma unroll
        for (int s = 0; s < 2; ++s)
            #pragma unroll
            for (int r = 0; r < 4; ++r) {
                int lr = (w << 5) + (s << 4) + (q << 2) + r;  // C row = q*4+r
                sbesti[lr] = bidx[s][r];
                sdot[lr]   = best[s][r];
            }
    }
    if (q == 0) {
        #pragma unroll
        for (int s = 0; s < 2; ++s) sn0[(w << 5) + (s << 4) + n15] = nsq[s];
    }
    __syncthreads();

    // ---- Epilogue A: out0 = emb0[bi] * sscale[bi], gathered from hot L2.
    // 32 lanes cover one row's 512 B; nt stores keep caches clean.
    size_t blockrow = (size_t)blockIdx.x * TILE_ROWS;
    #pragma unroll
    for (int pass = 0; pass < 16; ++pass) {
        int lr = (pass << 5) + (t >> 5);   // 32 rows per pass
        int v4 = t & 31;                   // float4 slot within the row
        int bi = sbesti[lr];
        float s = sscale[bi];              // LDS broadcast (same bi per half-wave)
        f32x4 e = *((const f32x4*)(emb0 + (size_t)bi * VDIM) + v4);
        f32x4 o;
        o[0] = e[0] * s; o[1] = e[1] * s; o[2] = e[2] * s; o[3] = e[3] * s;
        __builtin_nontemporal_store(o, (f32x4*)(out0 + (blockrow + lr) * (size_t)VDIM) + v4);
    }

    // ---- Epilogue B: per-row scalars (threads 0..511); LDS histogram
    if (t < TILE_ROWS) {
        size_t row = blockrow + t;
        int bi = sbesti[t];
        float dotv = sdot[t];
        float nn = sn0[t];
        float sc = TN / sqrtf(nn);                      // x = sc * x0
        float o1 = 2.f * TN * TN - 2.f * sc * dotv;     // ||x||^2=||e||^2=tn^2
        __builtin_nontemporal_store(o1, &out1[row]);
        float sm = sc - 1.f;
        __builtin_nontemporal_store(o1 + sm * sm * nn, &out2[row]);
        atomicAdd(&shist[bi], 1);
    }
    __syncthreads();

    // ---- Write u16 histogram partial (counts <= 512 fit u16); no atomics.
    if (t < KCODES)
        hist_part[((size_t)blockIdx.x << 9) + t] = (unsigned short)shist[t];
}

// Sum 256 x 512 u16 partials (256 KB) and compute entropy. One block.
__global__ __launch_bounds__(1024) void entropy_k(
        const unsigned short* __restrict__ hp,
        float* __restrict__ out) {
    __shared__ int   s2[1024];
    __shared__ float red[8];
    int t = threadIdx.x;
    int c = t & 511;          // code
    int half = t >> 9;        // each half sums 128 blocks
    int sum = 0;
    #pragma unroll 8
    for (int b = half * 128; b < half * 128 + 128; ++b)
        sum += hp[(b << 9) + c];
    s2[t] = sum;
    __syncthreads();
    if (t < 512) {
        float h = (float)(s2[t] + s2[t + 512]);
        float p = h / (float)NROWS;
        float term = (h > 0.f) ? p * logf(p) : 0.f;
        #pragma unroll
        for (int off = 32; off; off >>= 1) term += __shfl_xor(term, off);
        if ((t & 63) == 0) red[t >> 6] = term;
    }
    __syncthreads();
    if (t == 0) {
        float ssum = 0.f;
        #pragma unroll
        for (int i = 0; i < 8; i++) ssum += red[i];
        out[0] = -ssum;
    }
}

extern "C" void kernel_launch(void* const* d_in, const int* in_sizes, int n_in,
                              void* d_out, int out_size, void* d_ws, size_t ws_size,
                              hipStream_t stream) {
    const float* x0   = (const float*)d_in[0];
    const float* emb0 = (const float*)d_in[1];

    unsigned short* hist_part = (unsigned short*)d_ws;   // 256*512*2 = 256 KB

    float* out  = (float*)d_out;
    float* out0 = out;
    float* out1 = out0 + (size_t)NROWS * VDIM;
    float* out2 = out1 + NROWS;
    float* oent = out2 + NROWS;

    vq_fused<<<NBLK, 1024, 0, stream>>>(x0, emb0, hist_part, out0, out1, out2);
    entropy_k<<<1, 1024, 0, stream>>>(hist_part, oent);
}

// Round 5
// 158.900 us; speedup vs baseline: 1.1019x; 1.0476x over previous
//
#include <hip/hip_runtime.h>
#include <math.h>

// Problem constants
#define VDIM   128
#define KCODES 512
#define NROWS  (32 * 4096)       // 131072
#define TILE_ROWS 512            // rows per block (16 waves x 32 rows)
#define NBLK (NROWS / TILE_ROWS) // 256 blocks = exactly 1 per CU
#define TN 0.67882250993908565f  // 0.06 * sqrt(128)

typedef __attribute__((ext_vector_type(8))) short bf16x8;  // MFMA A/B frag (4 VGPR)
typedef __attribute__((ext_vector_type(4))) float f32x4;   // MFMA C/D frag / 16B ld-st

__device__ __forceinline__ unsigned short f2bf(float f) {
    unsigned u = __float_as_uint(f);
    unsigned r = u + 0x7FFFu + ((u >> 16) & 1u);   // round-to-nearest-even
    return (unsigned short)(r >> 16);
}

__device__ __forceinline__ bf16x8 pack8(f32x4 a, f32x4 b) {
    bf16x8 v;
    v[0] = (short)f2bf(a[0]); v[1] = (short)f2bf(a[1]);
    v[2] = (short)f2bf(a[2]); v[3] = (short)f2bf(a[3]);
    v[4] = (short)f2bf(b[0]); v[5] = (short)f2bf(b[1]);
    v[6] = (short)f2bf(b[2]); v[7] = (short)f2bf(b[3]);
    return v;
}

// ONE fused kernel, 16 waves x 32 rows, 1 block per CU.
// Key structure vs prior round:
//  - __launch_bounds__(1024, 1): VGPR cap 128 (not 64) so the 64-VGPR x0
//    payload is truly issued at t=0 and stays in flight under the norm +
//    table-build phases (prior round: compiler sank loads -> serial burst).
//  - NO barrier after the MFMA phase: per-row results are redistributed
//    inside each wave via compile-time shfl; each wave writes its own 32
//    rows. Waves drift independently -> store drain overlaps other waves'
//    MFMA. Barriers remain only around the shared table build + final hist.
// argmin(dist) == argmax(dot(x0,e)) since ||x|| = ||e|| = tn exactly.
__global__ __launch_bounds__(1024, 1) void vq_fused(
        const float* __restrict__ x0,
        const float* __restrict__ emb0,
        unsigned short* __restrict__ hist_part,
        float* __restrict__ out0,
        float* __restrict__ out1,
        float* __restrict__ out2) {
    __shared__ uint4 sB[8192];              // 128 KB fragment-linear bf16 table
    __shared__ float sscale[KCODES];        // TN / ||emb0_k||
    __shared__ int   shist[KCODES];         // per-block histogram

    int t = threadIdx.x;
    int w = t >> 6;           // wave 0..15
    int l = t & 63;
    int n15 = l & 15;         // MFMA m (A rows), n (B cols), col (C)
    int q = l >> 4;           // quad: input k = q*8 + j; C row = q*4 + r

    // ---- Issue x0 loads FIRST; held in VGPRs (64 regs) while norm/table
    // phases run. Plain loads: x0 may stay L3-resident across iterations.
    int rowbase = blockIdx.x * TILE_ROWS + (w << 5);
    f32x4 ax[2][4][2];
    #pragma unroll
    for (int s = 0; s < 2; ++s) {
        const float* xrow = x0 + (size_t)(rowbase + (s << 4) + n15) * VDIM + (q << 3);
        #pragma unroll
        for (int kc = 0; kc < 4; ++kc) {
            const f32x4* xp = (const f32x4*)(xrow + (kc << 5));
            ax[s][kc][0] = xp[0];
            ax[s][kc][1] = xp[1];
        }
    }

    if (t < KCODES) shist[t] = 0;

    // ---- Phase 1a: code norms. Wave w handles codes w*32 .. w*32+31.
    #pragma unroll 4
    for (int i = 0; i < 32; ++i) {
        int k = (w << 5) + i;
        const float* row = emb0 + (size_t)k * VDIM;
        float a = row[l];
        float b = row[l + 64];
        float ss = a * a + b * b;
        #pragma unroll
        for (int off = 32; off; off >>= 1) ss += __shfl_xor(ss, off);
        if (l == 0) sscale[k] = TN / sqrtf(ss);
    }
    __syncthreads();        // sscale + shist-zero visible

    // ---- Phase 1b: build fragment-linear table in LDS.
    // Granule g holds dims [d0, d0+8) of code k, where
    //   k = (g>>8)*16 + (g&15),  d0 = ((g>>4)&15)*8.
    #pragma unroll
    for (int i = 0; i < 8; ++i) {
        int g = (i << 10) + t;
        int k = ((g >> 8) << 4) | (g & 15);
        int d0 = ((g >> 4) & 15) << 3;
        float s = sscale[k];
        const f32x4* ep = (const f32x4*)(emb0 + (size_t)k * VDIM + d0);
        f32x4 a = ep[0], b = ep[1];
        f32x4 as, bs;
        as[0] = a[0] * s; as[1] = a[1] * s; as[2] = a[2] * s; as[3] = a[3] * s;
        bs[0] = b[0] * s; bs[1] = b[1] * s; bs[2] = b[2] * s; bs[3] = b[3] * s;
        ((bf16x8*)sB)[g] = pack8(as, bs);
    }

    // ---- Pack A from the (by now arrived) x0 registers
    bf16x8 afr[2][4];
    float nsq[2];
    #pragma unroll
    for (int s = 0; s < 2; ++s) {
        float p0 = 0.f, p1 = 0.f;
        #pragma unroll
        for (int kc = 0; kc < 4; ++kc) {
            f32x4 a = ax[s][kc][0], b = ax[s][kc][1];
            p0 = fmaf(a[0], a[0], p0); p1 = fmaf(a[1], a[1], p1);
            p0 = fmaf(a[2], a[2], p0); p1 = fmaf(a[3], a[3], p1);
            p0 = fmaf(b[0], b[0], p0); p1 = fmaf(b[1], b[1], p1);
            p0 = fmaf(b[2], b[2], p0); p1 = fmaf(b[3], b[3], p1);
            afr[s][kc] = pack8(a, b);
        }
        nsq[s] = p0 + p1;
        nsq[s] += __shfl_xor(nsq[s], 16, 64);   // reduce ||x0||^2 across quads
        nsq[s] += __shfl_xor(nsq[s], 32, 64);
    }

    float best[2][4];
    int   bidx[2][4];
    #pragma unroll
    for (int s = 0; s < 2; ++s)
        #pragma unroll
        for (int r = 0; r < 4; ++r) { best[s][r] = -3.4e38f; bidx[s][r] = 0; }

    const f32x4 zero4 = {0.f, 0.f, 0.f, 0.f};

    __syncthreads();        // table fully built; LAST block-wide sync before tail

    // ---- 32 chunks of 16 codes, B frags from LDS (stride-1, conflict-free)
    #pragma unroll 2
    for (int cn = 0; cn < 32; ++cn) {
        const bf16x8* bls = ((const bf16x8*)sB) + (cn << 8) + l;
        bf16x8 b0 = bls[0], b1 = bls[64], b2 = bls[128], b3 = bls[192];
        int nbase = (cn << 4) + n15;
        #pragma unroll
        for (int s = 0; s < 2; ++s) {
            f32x4 acc = __builtin_amdgcn_mfma_f32_16x16x32_bf16(afr[s][0], b0, zero4, 0, 0, 0);
            acc = __builtin_amdgcn_mfma_f32_16x16x32_bf16(afr[s][1], b1, acc, 0, 0, 0);
            acc = __builtin_amdgcn_mfma_f32_16x16x32_bf16(afr[s][2], b2, acc, 0, 0, 0);
            acc = __builtin_amdgcn_mfma_f32_16x16x32_bf16(afr[s][3], b3, acc, 0, 0, 0);
            #pragma unroll
            for (int r = 0; r < 4; ++r) {
                float d = acc[r];
                if (d > best[s][r]) { best[s][r] = d; bidx[s][r] = nbase; }
            }
        }
    }

    // ---- Reduce argmax across the 16 lanes (C cols) holding the same row.
    // Afterwards all 16 lanes of a quad hold identical (best,bidx) and the
    // value for local row i lives in best[i>>4][i&3] of any lane with
    // l>>4 == (i>>2)&3.
    #pragma unroll
    for (int m = 1; m <= 8; m <<= 1) {
        #pragma unroll
        for (int s = 0; s < 2; ++s)
            #pragma unroll
            for (int r = 0; r < 4; ++r) {
                float ov = __shfl_xor(best[s][r], m, 64);
                int   oi = __shfl_xor(bidx[s][r], m, 64);
                if (ov > best[s][r] || (ov == best[s][r] && oi < bidx[s][r])) {
                    best[s][r] = ov; bidx[s][r] = oi;
                }
            }
    }

    // ---- Wave-local epilogue A: out0 for this wave's 32 rows.
    // Pass p: lanes 0..31 -> row 2p, lanes 32..63 -> row 2p+1 (1 KB
    // contiguous store per pass). bi fetched via compile-time shfl.
    size_t wrow = (size_t)rowbase;
    #pragma unroll
    for (int p = 0; p < 16; ++p) {
        const int a0 = 2 * p, a1 = 2 * p + 1;
        int biLo = __shfl(bidx[a0 >> 4][a0 & 3], ((a0 >> 2) & 3) << 4, 64);
        int biHi = __shfl(bidx[a1 >> 4][a1 & 3], ((a1 >> 2) & 3) << 4, 64);
        int bi = (l >= 32) ? biHi : biLo;
        float s = sscale[bi];              // LDS broadcast (2 addrs per wave)
        int v4 = l & 31;
        size_t grow = wrow + (p << 1) + (l >> 5);
        f32x4 e = *((const f32x4*)(emb0 + (size_t)bi * VDIM) + v4);
        f32x4 o;
        o[0] = e[0] * s; o[1] = e[1] * s; o[2] = e[2] * s; o[3] = e[3] * s;
        __builtin_nontemporal_store(o, (f32x4*)(out0 + grow * (size_t)VDIM) + v4);
    }

    // ---- Wave-local epilogue B: out1/out2/hist. Lane i (<32) owns row i.
    // Iterate the 8 (s,r) register slots; 4 lanes active per slot.
    #pragma unroll
    for (int s = 0; s < 2; ++s)
        #pragma unroll
        for (int r = 0; r < 4; ++r) {
            int src = (l & 12) << 2;                 // ((i>>2)&3)<<4
            float dv = __shfl(best[s][r], src, 64);
            int   bv = __shfl(bidx[s][r], src, 64);
            float nn = __shfl(nsq[s], l & 15, 64);   // row (s<<4)+(i&15) norm^2
            bool act = (l < 32) && ((l >> 4) == s) && ((l & 3) == r);
            if (act) {
                size_t row = wrow + l;
                float sc = TN / sqrtf(nn);                   // x = sc * x0
                float o1 = 2.f * TN * TN - 2.f * sc * dv;    // ||x||=||e||=tn
                __builtin_nontemporal_store(o1, &out1[row]);
                float sm = sc - 1.f;
                __builtin_nontemporal_store(o1 + sm * sm * nn, &out2[row]);
                atomicAdd(&shist[bv], 1);
            }
        }

    __syncthreads();        // all waves' histogram contributions landed

    // ---- Write u16 histogram partial (counts <= 512 fit u16); no atomics.
    if (t < KCODES)
        hist_part[((size_t)blockIdx.x << 9) + t] = (unsigned short)shist[t];
}

// Sum 256 x 512 u16 partials (256 KB) and compute entropy. One block.
__global__ __launch_bounds__(1024) void entropy_k(
        const unsigned short* __restrict__ hp,
        float* __restrict__ out) {
    __shared__ int   s2[1024];
    __shared__ float red[8];
    int t = threadIdx.x;
    int c = t & 511;          // code
    int half = t >> 9;        // each half sums 128 blocks
    int sum = 0;
    #pragma unroll 8
    for (int b = half * 128; b < half * 128 + 128; ++b)
        sum += hp[(b << 9) + c];
    s2[t] = sum;
    __syncthreads();
    if (t < 512) {
        float h = (float)(s2[t] + s2[t + 512]);
        float p = h / (float)NROWS;
        float term = (h > 0.f) ? p * logf(p) : 0.f;
        #pragma unroll
        for (int off = 32; off; off >>= 1) term += __shfl_xor(term, off);
        if ((t & 63) == 0) red[t >> 6] = term;
    }
    __syncthreads();
    if (t == 0) {
        float ssum = 0.f;
        #pragma unroll
        for (int i = 0; i < 8; i++) ssum += red[i];
        out[0] = -ssum;
    }
}

extern "C" void kernel_launch(void* const* d_in, const int* in_sizes, int n_in,
                              void* d_out, int out_size, void* d_ws, size_t ws_size,
                              hipStream_t stream) {
    const float* x0   = (const float*)d_in[0];
    const float* emb0 = (const float*)d_in[1];

    unsigned short* hist_part = (unsigned short*)d_ws;   // 256*512*2 = 256 KB

    float* out  = (float*)d_out;
    float* out0 = out;
    float* out1 = out0 + (size_t)NROWS * VDIM;
    float* out2 = out1 + NROWS;
    float* oent = out2 + NROWS;

    vq_fused<<<NBLK, 1024, 0, stream>>>(x0, emb0, hist_part, out0, out1, out2);
    entropy_k<<<1, 1024, 0, stream>>>(hist_part, oent);
}